// Round 1
// baseline (1807.646 us; speedup 1.0000x reference)
//
#include <hip/hip_runtime.h>
#include <cstdint>
#include <cstddef>

#define NB 8
#define SL 1024
#define ED 1024
#define NH 16
#define DKH 64

typedef __attribute__((ext_vector_type(4))) float f32x4;
typedef __attribute__((ext_vector_type(8))) short short8;

// LDS row stride in bf16 elements: 32 payload + 8 pad (keeps 16B alignment, breaks pow2 bank stride)
#define LDSW 40

__device__ __forceinline__ unsigned short bf16_rn(float x) {
    unsigned int u = __float_as_uint(x);
    u += 0x7FFFu + ((u >> 16) & 1u);
    return (unsigned short)(u >> 16);
}
__device__ __forceinline__ float bf16_f(unsigned short h) {
    return __uint_as_float(((unsigned int)h) << 16);
}
__device__ __forceinline__ void split2(float x, unsigned short& hi, unsigned short& lo) {
    unsigned short h = bf16_rn(x);
    hi = h;
    lo = bf16_rn(x - bf16_f(h));
}

// Generic 64x64 tile GEMM core, BK=32, 256 threads (4 waves).
// A: M x K fp32 row-major (lda). B: if !BT, K x N row-major (ldb = row stride);
// if BT, B is N x K row-major (ldb = row stride) i.e. we compute A @ B^T.
// Wave w computes rows [m0+16w, m0+16w+16) x cols [n0, n0+64) as 4 MFMA tiles.
// Accuracy: bf16x2 split, 3 MFMA terms -> near-fp32.
template<bool BT>
__device__ __forceinline__ void gemm_core(
    const float* __restrict__ A, int lda,
    const float* __restrict__ B, int ldb,
    int Kd, int m0, int n0, f32x4 acc[4])
{
    __shared__ unsigned short Ahi[64 * LDSW];
    __shared__ unsigned short Alo[64 * LDSW];
    __shared__ unsigned short Bhi[64 * LDSW];
    __shared__ unsigned short Blo[64 * LDSW];

    const int tid  = threadIdx.x;
    const int wave = tid >> 6;
    const int lane = tid & 63;
    const int quad = lane >> 4;
    const int l16  = lane & 15;

#pragma unroll
    for (int j = 0; j < 4; j++) acc[j] = (f32x4)(0.0f);

    for (int k0 = 0; k0 < Kd; k0 += 32) {
        __syncthreads();
        // ---- stage A tile: 64 rows x 32 cols, float4 per thread x2 ----
        {
            const int r = tid >> 3;          // 0..31
            const int c = (tid & 7) * 4;     // 0..28
#pragma unroll
            for (int rr = r; rr < 64; rr += 32) {
                const float4 vv = *(const float4*)(A + (size_t)(m0 + rr) * lda + k0 + c);
                unsigned short h, l;
                split2(vv.x, h, l); Ahi[rr * LDSW + c + 0] = h; Alo[rr * LDSW + c + 0] = l;
                split2(vv.y, h, l); Ahi[rr * LDSW + c + 1] = h; Alo[rr * LDSW + c + 1] = l;
                split2(vv.z, h, l); Ahi[rr * LDSW + c + 2] = h; Alo[rr * LDSW + c + 2] = l;
                split2(vv.w, h, l); Ahi[rr * LDSW + c + 3] = h; Alo[rr * LDSW + c + 3] = l;
            }
        }
        // ---- stage B tile transposed into LDS [n][k] ----
        if (BT) {
            const int r = tid >> 3;
            const int c = (tid & 7) * 4;
#pragma unroll
            for (int rr = r; rr < 64; rr += 32) {
                const float4 vv = *(const float4*)(B + (size_t)(n0 + rr) * ldb + k0 + c);
                unsigned short h, l;
                split2(vv.x, h, l); Bhi[rr * LDSW + c + 0] = h; Blo[rr * LDSW + c + 0] = l;
                split2(vv.y, h, l); Bhi[rr * LDSW + c + 1] = h; Blo[rr * LDSW + c + 1] = l;
                split2(vv.z, h, l); Bhi[rr * LDSW + c + 2] = h; Blo[rr * LDSW + c + 2] = l;
                split2(vv.w, h, l); Bhi[rr * LDSW + c + 3] = h; Blo[rr * LDSW + c + 3] = l;
            }
        } else {
            const int n = tid & 63;
#pragma unroll
            for (int k = tid >> 6; k < 32; k += 4) {
                const float v = B[(size_t)(k0 + k) * ldb + n0 + n];
                unsigned short h, l;
                split2(v, h, l);
                Bhi[n * LDSW + k] = h;
                Blo[n * LDSW + k] = l;
            }
        }
        __syncthreads();

        // ---- fragments + MFMA (verified layouts: A[m=l16][k=quad*8+j], B[k=quad*8+j][n=l16]) ----
        const short8 ah = *(const short8*)&Ahi[(wave * 16 + l16) * LDSW + quad * 8];
        const short8 al = *(const short8*)&Alo[(wave * 16 + l16) * LDSW + quad * 8];
#pragma unroll
        for (int j = 0; j < 4; j++) {
            const short8 bh = *(const short8*)&Bhi[(j * 16 + l16) * LDSW + quad * 8];
            const short8 bl = *(const short8*)&Blo[(j * 16 + l16) * LDSW + quad * 8];
            acc[j] = __builtin_amdgcn_mfma_f32_16x16x32_bf16(al, bh, acc[j], 0, 0, 0);
            acc[j] = __builtin_amdgcn_mfma_f32_16x16x32_bf16(ah, bl, acc[j], 0, 0, 0);
            acc[j] = __builtin_amdgcn_mfma_f32_16x16x32_bf16(ah, bh, acc[j], 0, 0, 0);
        }
    }
}

// ---- input projection: out_heads[n][h][s][d] = (X @ W + b), X (N*S, E), W (E, E) ----
__global__ __launch_bounds__(256)
void k_proj(const float* __restrict__ A, const float* __restrict__ W,
            const float* __restrict__ bias, float* __restrict__ outHeads)
{
    const int m0 = blockIdx.x * 64;
    const int n0 = blockIdx.y * 64;
    f32x4 acc[4];
    gemm_core<false>(A, ED, W, ED, ED, m0, n0, acc);

    const int tid = threadIdx.x, wave = tid >> 6, lane = tid & 63;
    const int quad = lane >> 4, l16 = lane & 15;
#pragma unroll
    for (int j = 0; j < 4; j++) {
        const int col = n0 + j * 16 + l16;
        const int h = col >> 6, d = col & 63;
        const float b = bias[col];
#pragma unroll
        for (int r = 0; r < 4; r++) {
            const int m = m0 + wave * 16 + quad * 4 + r;
            const int n = m >> 10, s = m & 1023;
            outHeads[(((size_t)(n * NH + h)) * SL + s) * DKH + d] = acc[j][r] + b;
        }
    }
}

// ---- logits: attn[head][s][t] = (qh @ kh^T)/8, masked ----
__global__ __launch_bounds__(256)
void k_logits(const float* __restrict__ qh, const float* __restrict__ kh,
              const int* __restrict__ mask, float* __restrict__ attn)
{
    const int head = blockIdx.z;       // n*NH + h
    const int n = head >> 4;
    const int m0 = blockIdx.x * 64;
    const int n0 = blockIdx.y * 64;
    const float* Aq = qh + (size_t)head * SL * DKH;
    const float* Bk = kh + (size_t)head * SL * DKH;
    f32x4 acc[4];
    gemm_core<true>(Aq, DKH, Bk, DKH, DKH, m0, n0, acc);

    const int tid = threadIdx.x, wave = tid >> 6, lane = tid & 63;
    const int quad = lane >> 4, l16 = lane & 15;
    const float scale = 0.125f;  // 1/sqrt(64)
#pragma unroll
    for (int j = 0; j < 4; j++) {
        const int t = n0 + j * 16 + l16;
#pragma unroll
        for (int r = 0; r < 4; r++) {
            const int s = m0 + wave * 16 + quad * 4 + r;
            float v = acc[j][r] * scale;
            if (mask[((size_t)n * SL + s) * SL + t]) v = -1e9f;
            attn[((size_t)head * SL + s) * SL + t] = v;
        }
    }
}

// ---- row softmax in place, one block per row ----
__global__ __launch_bounds__(256)
void k_softmax(float* __restrict__ attn)
{
    const size_t row = blockIdx.x;
    float* p = attn + row * SL;
    const int tid = threadIdx.x;
    float4 v = ((float4*)p)[tid];

    __shared__ float red[256];
    float mx = fmaxf(fmaxf(v.x, v.y), fmaxf(v.z, v.w));
    red[tid] = mx;
    __syncthreads();
#pragma unroll
    for (int s = 128; s > 0; s >>= 1) {
        if (tid < s) red[tid] = fmaxf(red[tid], red[tid + s]);
        __syncthreads();
    }
    mx = red[0];
    __syncthreads();

    const float e0 = __expf(v.x - mx), e1 = __expf(v.y - mx);
    const float e2 = __expf(v.z - mx), e3 = __expf(v.w - mx);
    red[tid] = e0 + e1 + e2 + e3;
    __syncthreads();
#pragma unroll
    for (int s = 128; s > 0; s >>= 1) {
        if (tid < s) red[tid] += red[tid + s];
        __syncthreads();
    }
    const float inv = 1.0f / red[0];
    v.x = e0 * inv; v.y = e1 * inv; v.z = e2 * inv; v.w = e3 * inv;
    ((float4*)p)[tid] = v;
}

// ---- PV: oHeads[n][s][h*64+d] = P @ vh ----
__global__ __launch_bounds__(256)
void k_pv(const float* __restrict__ attn, const float* __restrict__ vh,
          float* __restrict__ oHeads)
{
    const int head = blockIdx.z;
    const int m0 = blockIdx.x * 64;
    const float* P = attn + (size_t)head * SL * SL;
    const float* V = vh + (size_t)head * SL * DKH;
    f32x4 acc[4];
    gemm_core<false>(P, SL, V, DKH, SL, m0, 0, acc);

    const int tid = threadIdx.x, wave = tid >> 6, lane = tid & 63;
    const int quad = lane >> 4, l16 = lane & 15;
    const int n = head >> 4, h = head & 15;
#pragma unroll
    for (int j = 0; j < 4; j++) {
        const int d = j * 16 + l16;
#pragma unroll
        for (int r = 0; r < 4; r++) {
            const int s = m0 + wave * 16 + quad * 4 + r;
            oHeads[((size_t)n * SL + s) * ED + h * DKH + d] = acc[j][r];
        }
    }
}

// ---- output projection: out[m][e] = oh @ wo + bo ----
__global__ __launch_bounds__(256)
void k_outproj(const float* __restrict__ A, const float* __restrict__ W,
               const float* __restrict__ bias, float* __restrict__ out)
{
    const int m0 = blockIdx.x * 64;
    const int n0 = blockIdx.y * 64;
    f32x4 acc[4];
    gemm_core<false>(A, ED, W, ED, ED, m0, n0, acc);

    const int tid = threadIdx.x, wave = tid >> 6, lane = tid & 63;
    const int quad = lane >> 4, l16 = lane & 15;
#pragma unroll
    for (int j = 0; j < 4; j++) {
        const int col = n0 + j * 16 + l16;
        const float b = bias[col];
#pragma unroll
        for (int r = 0; r < 4; r++) {
            const int m = m0 + wave * 16 + quad * 4 + r;
            out[(size_t)m * ED + col] = acc[j][r] + b;
        }
    }
}

extern "C" void kernel_launch(void* const* d_in, const int* in_sizes, int n_in,
                              void* d_out, int out_size, void* d_ws, size_t ws_size,
                              hipStream_t stream) {
    const float* q    = (const float*)d_in[0];
    const float* k    = (const float*)d_in[1];
    const float* v    = (const float*)d_in[2];
    const int*   mask = (const int*)d_in[3];
    const float* wq = (const float*)d_in[4];
    const float* bq = (const float*)d_in[5];
    const float* wk = (const float*)d_in[6];
    const float* bk = (const float*)d_in[7];
    const float* wv = (const float*)d_in[8];
    const float* bv = (const float*)d_in[9];
    const float* wo = (const float*)d_in[10];
    const float* bo = (const float*)d_in[11];

    float* out  = (float*)d_out;
    float* attn = out + (size_t)NB * SL * ED;   // second output: (N,H,S,S)

    float* ws = (float*)d_ws;
    const size_t hsz = (size_t)NB * NH * SL * DKH;  // 8388608
    float* qh = ws;
    float* kh = qh + hsz;
    float* vh = kh + hsz;
    float* oh = vh + hsz;

    const dim3 blk(256);
    const dim3 gproj(8192 / 64, ED / 64);

    hipLaunchKernelGGL(k_proj, gproj, blk, 0, stream, q, wq, bq, qh);
    hipLaunchKernelGGL(k_proj, gproj, blk, 0, stream, k, wk, bk, kh);
    hipLaunchKernelGGL(k_proj, gproj, blk, 0, stream, v, wv, bv, vh);

    const dim3 glog(SL / 64, SL / 64, NB * NH);
    hipLaunchKernelGGL(k_logits, glog, blk, 0, stream, qh, kh, mask, attn);

    hipLaunchKernelGGL(k_softmax, dim3(NB * NH * SL), blk, 0, stream, attn);

    hipLaunchKernelGGL(k_pv, dim3(SL / 64, 1, NB * NH), blk, 0, stream, attn, vh, oh);

    hipLaunchKernelGGL(k_outproj, gproj, blk, 0, stream, oh, wo, bo, out);
}